// Round 16
// baseline (72.627 us; speedup 1.0000x reference)
//
#include <hip/hip_runtime.h>
#include <hip/hip_bf16.h>

// B=8192, S=200, E=8, H1=64, H2=32
// att_in = [q, h, q-h, q*h] (32) -> relu(@W1[32,64]+b1) -> relu(@W2[64,32]+b2)
// score = @W3[32,1]+b3 ; mask s<len ; out[b,:] = sum_s score*hist[b,s,:]
//
// Transposed chain: h1^T = W1^T att^T ; h2^T = W2^T relu(h1)^T.
// pi-trick: W1 columns + b1 pre-permuted so stage-1 MFMA D-layout IS the
// stage-2 B-frag layout (zero LDS, zero transpose shuffles).
// This round: REGISTER DIET -> 3 waves/SIMD. hreg[13][8] (104 floats live)
// replaced by rotating hreg[4][8]; __launch_bounds__(256,3) caps at 170 regs.
#define BB 8192
#define SS 200

typedef __attribute__((ext_vector_type(8))) short short8;   // bf16x8 MFMA frag
typedef __attribute__((ext_vector_type(4))) float f32x4;    // fp32x4 MFMA acc

__device__ __forceinline__ unsigned short f2bf(float f) {
    union { float f; unsigned int u; } v; v.f = f;
    unsigned int r = v.u + 0x7FFFu + ((v.u >> 16) & 1u);    // RNE (prep only)
    return (unsigned short)(r >> 16);
}

// fast pack: low ushort = bf16(a), high = bf16(b); round-half-up (3 VALU).
__device__ __forceinline__ unsigned int packbf2(float a, float b) {
    union { float f; unsigned int u; } ua, ub;
    ua.f = a; ub.f = b;
    return __builtin_amdgcn_perm(ub.u + 0x8000u, ua.u + 0x8000u, 0x07060302u);
}

// ---- prep (2 blocks: 0 -> W1, 1 -> W2) ----
// wsW1[(n*64+l)*8+j] = W1[8g+j][pi(16n+c)],  pi(16n+c) = 32(n&1)+8(c>>2)+4(n>>1)+(c&3)
// wsW2[((kc*2+n)*64+l)*8+j] = W2[32kc+8g+j][16n+c]
__global__ void prep_kernel(const float* __restrict__ W1, const float* __restrict__ W2,
                            unsigned short* __restrict__ wsW1,
                            unsigned short* __restrict__ wsW2) {
    int t = threadIdx.x;             // 0..255
    int l = t & 63;
    int g = l >> 4, c = l & 15;
    if (blockIdx.x == 0) {
        int n = t >> 6;              // 0..3
        int pcol = 32 * (n & 1) + 8 * (c >> 2) + 4 * (n >> 1) + (c & 3);   // pi(16n + c)
#pragma unroll
        for (int j = 0; j < 8; ++j)
            wsW1[(n * 64 + l) * 8 + j] = f2bf(W1[(8 * g + j) * 64 + pcol]);
    } else {
        int kc = t >> 7, n = (t >> 6) & 1;
#pragma unroll
        for (int j = 0; j < 8; ++j)
            wsW2[((kc * 2 + n) * 64 + l) * 8 + j] = f2bf(W2[(32 * kc + 8 * g + j) * 32 + 16 * n + c]);
    }
}

// ---- main: 4 waves/block; wave owns one batch row; 13 subtiles, fully unrolled ----
__global__ __launch_bounds__(256, 3)
void din11_kernel(const float* __restrict__ query,       // [B,1,8]
                  const float* __restrict__ hist,        // [B,200,8]
                  const int* __restrict__ hlen,          // [B] int32
                  const unsigned short* __restrict__ wsW1,
                  const unsigned short* __restrict__ wsW2,
                  const float* __restrict__ b1,          // [64]
                  const float* __restrict__ b2,          // [32]
                  const float* __restrict__ W3,          // [32]
                  const float* __restrict__ b3,          // [1]
                  float* __restrict__ out)               // [B,1,8]
{
    const int tid  = threadIdx.x;
    const int wave = tid >> 6;
    const int l    = tid & 63;
    const int g    = l >> 4;     // k-block group
    const int c    = l & 15;     // position-within-subtile
    const int brow = blockIdx.x * 4 + wave;

    const int len = hlen[brow];

    short8 w1f[4];
#pragma unroll
    for (int n = 0; n < 4; ++n)
        w1f[n] = *reinterpret_cast<const short8*>(wsW1 + (n * 64 + l) * 8);
    short8 w2tf[2][2];
#pragma unroll
    for (int kc = 0; kc < 2; ++kc)
#pragma unroll
        for (int n2 = 0; n2 < 2; ++n2)
            w2tf[kc][n2] = *reinterpret_cast<const short8*>(wsW2 + ((kc * 2 + n2) * 64 + l) * 8);

    // permuted b1 as stage-1 C-operand: b1c[n][r] = b1[pi(16n+4g+r)] = b1[32(n&1)+4(n>>1)+8g+r]
    f32x4 b1c[4];
#pragma unroll
    for (int n = 0; n < 4; ++n)
        b1c[n] = *reinterpret_cast<const f32x4*>(b1 + 32 * (n & 1) + 4 * (n >> 1) + 8 * g);
    f32x4 b2c[2], W3v[2];
#pragma unroll
    for (int n2 = 0; n2 < 2; ++n2) {
        b2c[n2] = *reinterpret_cast<const f32x4*>(b2 + 16 * n2 + 4 * g);
        W3v[n2] = *reinterpret_cast<const f32x4*>(W3 + 16 * n2 + 4 * g);
    }
    const float b3s = b3[0];

    // att fold: v = aq[j] + bcv[j]*h[j]  (aq = alpha*q, bcv = beta + gamma*q)
    const float alpha = (g == 0 || g == 2) ? 1.0f : 0.0f;
    const float beta  = (g == 1) ? 1.0f : ((g == 2) ? -1.0f : 0.0f);
    const float gamma = (g == 3) ? 1.0f : 0.0f;
    const float4* qp = reinterpret_cast<const float4*>(query + (size_t)brow * 8);
    float4 qa = qp[0], qb = qp[1];
    float q[8] = {qa.x, qa.y, qa.z, qa.w, qb.x, qb.y, qb.z, qb.w};
    float aq[8], bcv[8];
#pragma unroll
    for (int j = 0; j < 8; ++j) { aq[j] = alpha * q[j]; bcv[j] = beta + gamma * q[j]; }

    const float* hrow = hist + (size_t)brow * SS * 8;
    float accO[8];
#pragma unroll
    for (int e = 0; e < 8; ++e) accO[e] = 0.0f;

    // rotating 4-slot h buffer (all indices compile-time after full unroll)
    float hreg[4][8];

    auto loadH = [&](int x) {
        int s = 16 * x + c;
        if (16 * x + 15 >= SS) s = min(s, SS - 1);   // folds away except last subtile
        const float4* p = reinterpret_cast<const float4*>(hrow + (size_t)s * 8);
        float4 v0 = p[0], v1 = p[1];
        float* h = hreg[x & 3];
        h[0]=v0.x; h[1]=v0.y; h[2]=v0.z; h[3]=v0.w;
        h[4]=v1.x; h[5]=v1.y; h[6]=v1.z; h[7]=v1.w;
    };

    // pipeline state: stage-2 B-frags for two subtile parities (static [x&1] idx)
    union u_s8 { unsigned int u[4]; short8 s; };
    u_s8 hb0_[2], hb1_[2];

    // S1: att-pack -> stage-1' MFMA (4x) -> relu+pack into hb frags
    auto S1 = [&](int x) {
        const float* h = hreg[x & 3];
        u_s8 uf;
#pragma unroll
        for (int m = 0; m < 4; ++m)
            uf.u[m] = packbf2(fmaf(bcv[2*m], h[2*m], aq[2*m]),
                              fmaf(bcv[2*m+1], h[2*m+1], aq[2*m+1]));
        f32x4 a1[4];
#pragma unroll
        for (int n = 0; n < 4; ++n)
            a1[n] = __builtin_amdgcn_mfma_f32_16x16x32_bf16(w1f[n], uf.s, b1c[n], 0, 0, 0);
        u_s8& hb0 = hb0_[x & 1];
        u_s8& hb1 = hb1_[x & 1];
#pragma unroll
        for (int q2 = 0; q2 < 2; ++q2) {
            hb0.u[q2]     = packbf2(fmaxf(a1[0][2*q2], 0.f), fmaxf(a1[0][2*q2+1], 0.f));
            hb0.u[2 + q2] = packbf2(fmaxf(a1[2][2*q2], 0.f), fmaxf(a1[2][2*q2+1], 0.f));
            hb1.u[q2]     = packbf2(fmaxf(a1[1][2*q2], 0.f), fmaxf(a1[1][2*q2+1], 0.f));
            hb1.u[2 + q2] = packbf2(fmaxf(a1[3][2*q2], 0.f), fmaxf(a1[3][2*q2+1], 0.f));
        }
    };

    // S2: stage-2' MFMA (4x) -> W3 dot -> butterfly -> mask -> pool
    auto S2 = [&](int x) {
        const float* h = hreg[x & 3];
        u_s8& hb0 = hb0_[x & 1];
        u_s8& hb1 = hb1_[x & 1];
        f32x4 a2[2];
#pragma unroll
        for (int n2 = 0; n2 < 2; ++n2) {
            a2[n2] = __builtin_amdgcn_mfma_f32_16x16x32_bf16(w2tf[0][n2], hb0.s, b2c[n2], 0, 0, 0);
            a2[n2] = __builtin_amdgcn_mfma_f32_16x16x32_bf16(w2tf[1][n2], hb1.s, a2[n2], 0, 0, 0);
        }
        float p0 = 0.f, p1 = 0.f;
#pragma unroll
        for (int r = 0; r < 4; ++r) {
            p0 = fmaf(fmaxf(a2[0][r], 0.f), W3v[0][r], p0);
            p1 = fmaf(fmaxf(a2[1][r], 0.f), W3v[1][r], p1);
        }
        float p = p0 + p1;
        p += __shfl_xor(p, 16); p += __shfl_xor(p, 32);
        float sc = (16 * x + c < len) ? (p + b3s) : 0.0f;
#pragma unroll
        for (int e = 0; e < 8; ++e) accO[e] = fmaf(sc, h[e], accO[e]);
    };

    // ---- pipeline: load(t+3) | S1(t+1) | S2(t), fully unrolled ----
    // slot liveness: hreg[x&3] written at iter x-3, read S1 at x-1, S2 at x,
    // next overwritten by loadH(x+4) at iter x+1 -> no conflict.
    loadH(0);
    loadH(1);
    loadH(2);
    S1(0);
#pragma unroll
    for (int it = 0; it < 13; ++it) {
        if (it + 3 < 13) loadH(it + 3);
        if (it + 1 < 13) S1(it + 1);
        S2(it);
    }

    // ---- reduce over the 16 position-lanes (g-copies identical) ----
#pragma unroll
    for (int m = 1; m < 16; m <<= 1)
#pragma unroll
        for (int e = 0; e < 8; ++e) accO[e] += __shfl_xor(accO[e], m);

    if (l == 0) {
        float4* op = reinterpret_cast<float4*>(out + (size_t)brow * 8);
        op[0] = make_float4(accO[0], accO[1], accO[2], accO[3]);
        op[1] = make_float4(accO[4], accO[5], accO[6], accO[7]);
    }
}

extern "C" void kernel_launch(void* const* d_in, const int* in_sizes, int n_in,
                              void* d_out, int out_size, void* d_ws, size_t ws_size,
                              hipStream_t stream) {
    const float* query = (const float*)d_in[0];
    const float* hist  = (const float*)d_in[1];
    const int*   hlen  = (const int*)d_in[2];
    const float* W1    = (const float*)d_in[3];
    const float* b1    = (const float*)d_in[4];
    const float* W2    = (const float*)d_in[5];
    const float* b2    = (const float*)d_in[6];
    const float* W3    = (const float*)d_in[7];
    const float* b3    = (const float*)d_in[8];
    float*       out   = (float*)d_out;

    unsigned short* wsW1 = (unsigned short*)d_ws;          // 4KB
    unsigned short* wsW2 = wsW1 + 4 * 64 * 8;              // 4KB

    prep_kernel<<<2, 256, 0, stream>>>(W1, W2, wsW1, wsW2);
    din11_kernel<<<BB / 4, 256, 0, stream>>>(query, hist, hlen, wsW1, wsW2,
                                             b1, b2, W3, b3, out);
}

// Round 17
// 39.057 us; speedup vs baseline: 1.8595x; 1.8595x over previous
//
#include <hip/hip_runtime.h>
#include <hip/hip_bf16.h>

// B=8192, S=200, E=8, H1=64, H2=32
// att_in = [q, h, q-h, q*h] (32) -> relu(@W1[32,64]+b1) -> relu(@W2[64,32]+b2)
// score = @W3[32,1]+b3 ; mask s<len ; out[b,:] = sum_s score*hist[b,s,:]
//
// Veff rank reduction: h1_i = base_i(q) + sum_j Veff[j,i](q) * h_j  where
//   base = b1 + (W1[0:8]+W1[16:24])^T q   (via setup MFMA)
//   Veff[j,i] = W1[8+j,i] - W1[16+j,i] + W1[24+j,i]*q_j  (built per row)
// 32x32x16 MFMA; pi bit-permutation on W1 columns/b1 makes stage-1 D = stage-2
// B-frags in-register (no LDS, no shuffles). 32 positions/iter, 7 iters.
#define BB 8192
#define SS 200

typedef __attribute__((ext_vector_type(8)))  short  short8;   // bf16x8 frag
typedef __attribute__((ext_vector_type(4)))  float  f32x4;
typedef __attribute__((ext_vector_type(16))) float  f32x16;   // 32x32 acc

__device__ __forceinline__ unsigned short f2bf(float f) {
    union { float f; unsigned int u; } v; v.f = f;
    unsigned int r = v.u + 0x7FFFu + ((v.u >> 16) & 1u);    // RNE (prep only)
    return (unsigned short)(r >> 16);
}
// fast pack: low = bf16(a), high = bf16(b); round-half-up (3 VALU)
__device__ __forceinline__ unsigned int packbf2(float a, float b) {
    union { float f; unsigned int u; } ua, ub;
    ua.f = a; ub.f = b;
    return __builtin_amdgcn_perm(ub.u + 0x8000u, ua.u + 0x8000u, 0x07060302u);
}
// pi: s bits [t|b1 b0|h|r1 r0] -> [t|b1|h|b0|r1 r0]
__device__ __forceinline__ int pi_perm(int s) {
    int t = s >> 5, b = (s >> 3) & 3, h = (s >> 2) & 1, r = s & 3;
    return 32 * t + 16 * (b >> 1) + 8 * h + 4 * (b & 1) + r;
}

// ---- prep: P0/P1/P2 (Veff precursors, pi-ordered), b1pi, W2 frags ----
__global__ void prep_kernel(const float* __restrict__ W1, const float* __restrict__ W2,
                            const float* __restrict__ b1,
                            float* __restrict__ wsP1, float* __restrict__ wsP2,
                            float* __restrict__ wsb1p,
                            unsigned short* __restrict__ wsP0,
                            unsigned short* __restrict__ wsW2f) {
    int tid = threadIdx.x;
    for (int e = tid; e < 1024; e += 256) {     // [t:2][l:64][j:8]
        int l = (e >> 3) & 63, j = e & 7, t = e >> 9;
        if (l < 32) {
            int i = pi_perm(32 * t + l);
            wsP0[e] = f2bf(W1[j * 64 + i] + W1[(16 + j) * 64 + i]);
            wsP1[e] = W1[(8 + j) * 64 + i] - W1[(16 + j) * 64 + i];
            wsP2[e] = W1[(24 + j) * 64 + i];
        } else { wsP0[e] = 0; wsP1[e] = 0.f; wsP2[e] = 0.f; }
    }
    for (int e = tid; e < 2048; e += 256) {     // [m:4][l:64][j:8]
        int m = e >> 9, l = (e >> 3) & 63, j = e & 7;
        wsW2f[e] = f2bf(W2[(16 * m + 8 * (l >> 5) + j) * 32 + (l & 31)]);
    }
    if (tid < 64) wsb1p[tid] = b1[pi_perm(tid)];
}

// ---- main: 4 waves/block; wave owns one row; 7 super-subtiles of 32 pos ----
__global__ __launch_bounds__(256)
void din12_kernel(const float* __restrict__ query,      // [B,1,8]
                  const float* __restrict__ hist,       // [B,200,8]
                  const int* __restrict__ hlen,         // [B]
                  const float* __restrict__ wsP1, const float* __restrict__ wsP2,
                  const float* __restrict__ wsb1p,
                  const unsigned short* __restrict__ wsP0,
                  const unsigned short* __restrict__ wsW2f,
                  const float* __restrict__ b2,         // [32]
                  const float* __restrict__ W3,         // [32]
                  const float* __restrict__ b3,         // [1]
                  float* __restrict__ out)              // [B,1,8]
{
    const int tid  = threadIdx.x;
    const int wave = tid >> 6;
    const int l    = tid & 63;
    const int col  = l & 31;            // position within super-subtile
    const int hi   = l >> 5;            // k-group
    const int brow = blockIdx.x * 4 + wave;

    const int len = hlen[brow];
    const unsigned hm = (hi == 0) ? 0xFFFFFFFFu : 0u;   // zero k=8..15

    const float4* qp = reinterpret_cast<const float4*>(query + (size_t)brow * 8);
    float4 qa = qp[0], qb = qp[1];
    float q[8] = {qa.x, qa.y, qa.z, qa.w, qb.x, qb.y, qb.z, qb.w};

    // Veff A-frags (stage 1)
    short8 a1f[2];
#pragma unroll
    for (int t = 0; t < 2; ++t) {
        const f32x4* p1 = reinterpret_cast<const f32x4*>(wsP1 + (t * 64 + l) * 8);
        const f32x4* p2 = reinterpret_cast<const f32x4*>(wsP2 + (t * 64 + l) * 8);
        f32x4 p1a = p1[0], p1b = p1[1], p2a = p2[0], p2b = p2[1];
        union { unsigned u[4]; short8 s; } uf;
        uf.u[0] = packbf2(fmaf(q[0], p2a[0], p1a[0]), fmaf(q[1], p2a[1], p1a[1]));
        uf.u[1] = packbf2(fmaf(q[2], p2a[2], p1a[2]), fmaf(q[3], p2a[3], p1a[3]));
        uf.u[2] = packbf2(fmaf(q[4], p2b[0], p1b[0]), fmaf(q[5], p2b[1], p1b[1]));
        uf.u[3] = packbf2(fmaf(q[6], p2b[2], p1b[2]), fmaf(q[7], p2b[3], p1b[3]));
        a1f[t] = uf.s;
    }

    // W2 A-frags (stage 2, 4 K-chains)
    short8 w2f[4];
#pragma unroll
    for (int m = 0; m < 4; ++m)
        w2f[m] = *reinterpret_cast<const short8*>(wsW2f + (m * 64 + l) * 8);

    // b2 / W3 in D-layout (row = (p&3)+8*(p>>2)+4*hi)
    f32x16 b2c16, W3v16;
#pragma unroll
    for (int u = 0; u < 4; ++u) {
        f32x4 vb = *reinterpret_cast<const f32x4*>(b2 + 8 * u + 4 * hi);
        f32x4 vw = *reinterpret_cast<const f32x4*>(W3 + 8 * u + 4 * hi);
#pragma unroll
        for (int i = 0; i < 4; ++i) { b2c16[4 * u + i] = vb[i]; W3v16[4 * u + i] = vw[i]; }
    }
    const float b3s = b3[0];

    // base1d[t] = P0^T q + b1pi via setup MFMA (C = b1pi broadcast)
    union u_s8 { unsigned u[4]; short8 s; };
    u_s8 uq;
    uq.u[0] = packbf2(q[0], q[1]) & hm;
    uq.u[1] = packbf2(q[2], q[3]) & hm;
    uq.u[2] = packbf2(q[4], q[5]) & hm;
    uq.u[3] = packbf2(q[6], q[7]) & hm;
    f32x16 base1d[2];
#pragma unroll
    for (int t = 0; t < 2; ++t) {
        short8 p0f = *reinterpret_cast<const short8*>(wsP0 + (t * 64 + l) * 8);
        f32x16 c;
#pragma unroll
        for (int u = 0; u < 4; ++u) {
            f32x4 v = *reinterpret_cast<const f32x4*>(wsb1p + 32 * t + 8 * u + 4 * hi);
#pragma unroll
            for (int i = 0; i < 4; ++i) c[4 * u + i] = v[i];
        }
        base1d[t] = __builtin_amdgcn_mfma_f32_32x32x16_bf16(p0f, uq.s, c, 0, 0, 0);
    }

    const float* hrow = hist + (size_t)brow * SS * 8;
    float accO[8];
#pragma unroll
    for (int e = 0; e < 8; ++e) accO[e] = 0.0f;

    float hreg[3][8];           // rotating, static idx after full unroll
    u_s8 b2B_[2][4];            // stage-2 B-frags, 2 parities

    auto loadH = [&](int x) {
        int s = 32 * x + col;
        if (32 * x + 31 >= SS) s = min(s, SS - 1);      // folds away except x=6
        const float4* p = reinterpret_cast<const float4*>(hrow + (size_t)s * 8);
        float4 v0 = p[0], v1 = p[1];
        float* h = hreg[x % 3];
        h[0]=v0.x; h[1]=v0.y; h[2]=v0.z; h[3]=v0.w;
        h[4]=v1.x; h[5]=v1.y; h[6]=v1.z; h[7]=v1.w;
    };

    // S1: pack h -> 2 MFMA (Veff, bias-in-C) -> relu+pack into stage-2 B-frags
    auto S1 = [&](int x) {
        const float* h = hreg[x % 3];
        u_s8 hb;
        hb.u[0] = packbf2(h[0], h[1]) & hm;
        hb.u[1] = packbf2(h[2], h[3]) & hm;
        hb.u[2] = packbf2(h[4], h[5]) & hm;
        hb.u[3] = packbf2(h[6], h[7]) & hm;
        f32x16 a1_0 = __builtin_amdgcn_mfma_f32_32x32x16_bf16(a1f[0], hb.s, base1d[0], 0, 0, 0);
        f32x16 a1_1 = __builtin_amdgcn_mfma_f32_32x32x16_bf16(a1f[1], hb.s, base1d[1], 0, 0, 0);
        // pi makes D-slot (t, p=8*(m&1)+2d (+1)) = stage-2 B elem (m, j=2d (+1))
#pragma unroll
        for (int m = 0; m < 4; ++m) {
#pragma unroll
            for (int d = 0; d < 4; ++d) {
                int p0 = 8 * (m & 1) + 2 * d;
                float lo, hi2;
                if (m >> 1) { lo = a1_1[p0]; hi2 = a1_1[p0 + 1]; }
                else        { lo = a1_0[p0]; hi2 = a1_0[p0 + 1]; }
                b2B_[x & 1][m].u[d] = packbf2(fmaxf(lo, 0.f), fmaxf(hi2, 0.f));
            }
        }
    };

    // S2: 4 chained MFMA (bias-in-C) -> W3 dot -> 1 shfl -> mask -> pool
    auto S2 = [&](int x) {
        const float* h = hreg[x % 3];
        f32x16 a2 = __builtin_amdgcn_mfma_f32_32x32x16_bf16(w2f[0], b2B_[x & 1][0].s, b2c16, 0, 0, 0);
        a2 = __builtin_amdgcn_mfma_f32_32x32x16_bf16(w2f[1], b2B_[x & 1][1].s, a2, 0, 0, 0);
        a2 = __builtin_amdgcn_mfma_f32_32x32x16_bf16(w2f[2], b2B_[x & 1][2].s, a2, 0, 0, 0);
        a2 = __builtin_amdgcn_mfma_f32_32x32x16_bf16(w2f[3], b2B_[x & 1][3].s, a2, 0, 0, 0);
        float s0 = 0.f, s1 = 0.f, s2 = 0.f, s3 = 0.f;
#pragma unroll
        for (int r = 0; r < 4; ++r) {
            s0 = fmaf(fmaxf(a2[r],      0.f), W3v16[r],      s0);
            s1 = fmaf(fmaxf(a2[4 + r],  0.f), W3v16[4 + r],  s1);
            s2 = fmaf(fmaxf(a2[8 + r],  0.f), W3v16[8 + r],  s2);
            s3 = fmaf(fmaxf(a2[12 + r], 0.f), W3v16[12 + r], s3);
        }
        float p = (s0 + s1) + (s2 + s3);
        p += __shfl_xor(p, 32);            // sum the two hi-groups' 16-row partials
        float sc = (32 * x + col < len) ? (p + b3s) : 0.0f;
#pragma unroll
        for (int e = 0; e < 8; ++e) accO[e] = fmaf(sc, h[e], accO[e]);
    };

    // pipeline: load(t+2) | S1(t+1) | S2(t), fully unrolled (7 iters)
    loadH(0);
    loadH(1);
    S1(0);
#pragma unroll
    for (int it = 0; it < 7; ++it) {
        if (it + 2 < 7) loadH(it + 2);
        if (it + 1 < 7) S1(it + 1);
        S2(it);
    }

    // reduce over the 32 position-lanes (hi-copies identical)
#pragma unroll
    for (int m = 1; m < 32; m <<= 1)
#pragma unroll
        for (int e = 0; e < 8; ++e) accO[e] += __shfl_xor(accO[e], m);

    if (l == 0) {
        float4* op = reinterpret_cast<float4*>(out + (size_t)brow * 8);
        op[0] = make_float4(accO[0], accO[1], accO[2], accO[3]);
        op[1] = make_float4(accO[4], accO[5], accO[6], accO[7]);
    }
}

extern "C" void kernel_launch(void* const* d_in, const int* in_sizes, int n_in,
                              void* d_out, int out_size, void* d_ws, size_t ws_size,
                              hipStream_t stream) {
    const float* query = (const float*)d_in[0];
    const float* hist  = (const float*)d_in[1];
    const int*   hlen  = (const int*)d_in[2];
    const float* W1    = (const float*)d_in[3];
    const float* b1    = (const float*)d_in[4];
    const float* W2    = (const float*)d_in[5];
    const float* b2    = (const float*)d_in[6];
    const float* W3    = (const float*)d_in[7];
    const float* b3    = (const float*)d_in[8];
    float*       out   = (float*)d_out;

    char* w = (char*)d_ws;
    float*          wsP1  = (float*)(w);             // 4096 B
    float*          wsP2  = (float*)(w + 4096);      // 4096 B
    float*          wsb1p = (float*)(w + 8192);      // 256 B
    unsigned short* wsP0  = (unsigned short*)(w + 8448);    // 2048 B
    unsigned short* wsW2f = (unsigned short*)(w + 10496);   // 4096 B

    prep_kernel<<<1, 256, 0, stream>>>(W1, W2, b1, wsP1, wsP2, wsb1p, wsP0, wsW2f);
    din12_kernel<<<BB / 4, 256, 0, stream>>>(query, hist, hlen, wsP1, wsP2, wsb1p,
                                             wsP0, wsW2f, b2, W3, b3, out);
}

// Round 19
// 38.599 us; speedup vs baseline: 1.8815x; 1.0119x over previous
//
#include <hip/hip_runtime.h>
#include <hip/hip_bf16.h>

// B=8192, S=200, E=8, H1=64, H2=32
// att_in = [q, h, q-h, q*h] (32) -> relu(@W1[32,64]+b1) -> relu(@W2[64,32]+b2)
// score = @W3[32,1]+b3 ; mask s<len ; out[b,:] = sum_s score*hist[b,s,:]
//
// Veff rank reduction with K-AUGMENTATION (32x32x16 MFMA):
//   h1_i = sum_{k=0..7} Veff[k,i]*h_k + sum_{k=8..15} P0[k-8,i]*q_{k-8} + b1_i
//   Veff[k,i] = P1[k,i] + q_k*P2[k,i];  P0/P1/P2 from W1 blocks (prep).
//   hi=0 lanes carry the h half (runtime q-fold), hi=1 lanes the q half
//   (static from prep); b1 rides in the shared read-only C-operand.
// pi bit-permutation on W1 columns/b1 makes stage-1 D = stage-2 B-frags
// in-register (validated R17). DUAL-ROW: each wave runs 2 independent row
// chains interleaved -> 2x stall-filling ILP at the fixed 2-waves/SIMD cap.
#define BB 8192
#define SS 200

typedef __attribute__((ext_vector_type(8)))  short  short8;
typedef __attribute__((ext_vector_type(4)))  float  f32x4;
typedef __attribute__((ext_vector_type(16))) float  f32x16;

__device__ __forceinline__ unsigned short f2bf(float f) {
    union { float f; unsigned int u; } v; v.f = f;
    unsigned int r = v.u + 0x7FFFu + ((v.u >> 16) & 1u);    // RNE (prep only)
    return (unsigned short)(r >> 16);
}
// fast pack: low = bf16(a), high = bf16(b); round-half-up (3 VALU)
__device__ __forceinline__ unsigned int packbf2(float a, float b) {
    union { float f; unsigned int u; } ua, ub;
    ua.f = a; ub.f = b;
    return __builtin_amdgcn_perm(ub.u + 0x8000u, ua.u + 0x8000u, 0x07060302u);
}
// pi: s bits [t|b1 b0|h|r1 r0] -> [t|b1|h|b0|r1 r0]   (validated R17)
__device__ __forceinline__ int pi_perm(int s) {
    int t = s >> 5, b = (s >> 3) & 3, h = (s >> 2) & 1, r = s & 3;
    return 32 * t + 16 * (b >> 1) + 8 * h + 4 * (b & 1) + r;
}

// ---- prep ----
// wsA[t][l][j] = float2 {PA,PB}:  frag[j] = bf16(PA + q[j]*PB)
//   hi=0: PA=P1[j,i], PB=P2[j,i]   (i = pi(32t + (l&31)))
//   hi=1: PA=P0[j,i], PB=0
// wsb1p[64] = b1[pi(idx)] ; wsW2f = W2 A-frags (as R17)
__global__ void prep_kernel(const float* __restrict__ W1, const float* __restrict__ W2,
                            const float* __restrict__ b1,
                            float* __restrict__ wsA, float* __restrict__ wsb1p,
                            unsigned short* __restrict__ wsW2f) {
    int tid = threadIdx.x;
    for (int e = tid; e < 1024; e += 256) {     // [t:2][l:64][j:8]
        int t = e >> 9, l = (e >> 3) & 63, j = e & 7;
        int hi = l >> 5, i = pi_perm(32 * t + (l & 31));
        float pa, pb;
        if (hi == 0) { pa = W1[(8 + j) * 64 + i] - W1[(16 + j) * 64 + i];
                       pb = W1[(24 + j) * 64 + i]; }
        else         { pa = W1[j * 64 + i] + W1[(16 + j) * 64 + i];
                       pb = 0.0f; }
        wsA[2 * e] = pa; wsA[2 * e + 1] = pb;
    }
    for (int e = tid; e < 2048; e += 256) {     // [m:4][l:64][j:8]
        int m = e >> 9, l = (e >> 3) & 63, j = e & 7;
        wsW2f[e] = f2bf(W2[(16 * m + 8 * (l >> 5) + j) * 32 + (l & 31)]);
    }
    if (tid < 64) wsb1p[tid] = b1[pi_perm(tid)];
}

// ---- main: 4 waves/block; wave owns TWO adjacent rows; 7 iters of 32 pos ----
__global__ __launch_bounds__(256)
void din13_kernel(const float* __restrict__ query,      // [B,1,8]
                  const float* __restrict__ hist,       // [B,200,8]
                  const int* __restrict__ hlen,         // [B]
                  const float* __restrict__ wsA,
                  const float* __restrict__ wsb1p,
                  const unsigned short* __restrict__ wsW2f,
                  const float* __restrict__ b2,         // [32]
                  const float* __restrict__ W3,         // [32]
                  const float* __restrict__ b3,         // [1]
                  float* __restrict__ out)              // [B,1,8]
{
    const int tid  = threadIdx.x;
    const int wave = tid >> 6;
    const int l    = tid & 63;
    const int col  = l & 31;
    const int hi   = l >> 5;
    const int wid  = blockIdx.x * 4 + wave;     // 0..4095
    const int brow0 = 2 * wid, brow1 = 2 * wid + 1;

    const int len0 = hlen[brow0], len1 = hlen[brow1];

    float q0[8], q1[8];
    {
        const float4* p = reinterpret_cast<const float4*>(query + (size_t)brow0 * 8);
        float4 a = p[0], b = p[1];
        q0[0]=a.x; q0[1]=a.y; q0[2]=a.z; q0[3]=a.w; q0[4]=b.x; q0[5]=b.y; q0[6]=b.z; q0[7]=b.w;
    }
    {
        const float4* p = reinterpret_cast<const float4*>(query + (size_t)brow1 * 8);
        float4 a = p[0], b = p[1];
        q1[0]=a.x; q1[1]=a.y; q1[2]=a.z; q1[3]=a.w; q1[4]=b.x; q1[5]=b.y; q1[6]=b.z; q1[7]=b.w;
    }

    // stage-1 A-frags per row (q-folded Veff / static P0)
    short8 a1fA[2], a1fB[2];
#pragma unroll
    for (int t = 0; t < 2; ++t) {
        const f32x4* pw = reinterpret_cast<const f32x4*>(wsA + (t * 64 + l) * 16);
        f32x4 w0 = pw[0], w1 = pw[1], w2 = pw[2], w3v = pw[3];
        union { unsigned u[4]; short8 s; } ua, ub;
        ua.u[0] = packbf2(fmaf(q0[0], w0[1], w0[0]),  fmaf(q0[1], w0[3], w0[2]));
        ua.u[1] = packbf2(fmaf(q0[2], w1[1], w1[0]),  fmaf(q0[3], w1[3], w1[2]));
        ua.u[2] = packbf2(fmaf(q0[4], w2[1], w2[0]),  fmaf(q0[5], w2[3], w2[2]));
        ua.u[3] = packbf2(fmaf(q0[6], w3v[1], w3v[0]), fmaf(q0[7], w3v[3], w3v[2]));
        ub.u[0] = packbf2(fmaf(q1[0], w0[1], w0[0]),  fmaf(q1[1], w0[3], w0[2]));
        ub.u[1] = packbf2(fmaf(q1[2], w1[1], w1[0]),  fmaf(q1[3], w1[3], w1[2]));
        ub.u[2] = packbf2(fmaf(q1[4], w2[1], w2[0]),  fmaf(q1[5], w2[3], w2[2]));
        ub.u[3] = packbf2(fmaf(q1[6], w3v[1], w3v[0]), fmaf(q1[7], w3v[3], w3v[2]));
        a1fA[t] = ua.s; a1fB[t] = ub.s;
    }

    // stage-1 B-frag constant half (q values, slots 8..15) per row
    unsigned uqcA[4] = {packbf2(q0[0], q0[1]), packbf2(q0[2], q0[3]),
                        packbf2(q0[4], q0[5]), packbf2(q0[6], q0[7])};
    unsigned uqcB[4] = {packbf2(q1[0], q1[1]), packbf2(q1[2], q1[3]),
                        packbf2(q1[4], q1[5]), packbf2(q1[6], q1[7])};

    // shared read-only C-operands: b1 (stage 1, both tiles), b2 (stage 2)
    f32x16 b1c16[2];
#pragma unroll
    for (int t = 0; t < 2; ++t)
#pragma unroll
        for (int u = 0; u < 4; ++u) {
            f32x4 v = *reinterpret_cast<const f32x4*>(wsb1p + 32 * t + 8 * u + 4 * hi);
#pragma unroll
            for (int i = 0; i < 4; ++i) b1c16[t][4 * u + i] = v[i];
        }
    f32x16 b2c16, W3v16;
#pragma unroll
    for (int u = 0; u < 4; ++u) {
        f32x4 vb = *reinterpret_cast<const f32x4*>(b2 + 8 * u + 4 * hi);
        f32x4 vw = *reinterpret_cast<const f32x4*>(W3 + 8 * u + 4 * hi);
#pragma unroll
        for (int i = 0; i < 4; ++i) { b2c16[4 * u + i] = vb[i]; W3v16[4 * u + i] = vw[i]; }
    }
    const float b3s = b3[0];

    short8 w2f[4];
#pragma unroll
    for (int m = 0; m < 4; ++m)
        w2f[m] = *reinterpret_cast<const short8*>(wsW2f + (m * 64 + l) * 8);

    const float* hrow0 = hist + (size_t)brow0 * SS * 8;
    const float* hrow1 = hist + (size_t)brow1 * SS * 8;

    float accA[8], accB[8];
#pragma unroll
    for (int e = 0; e < 8; ++e) { accA[e] = 0.0f; accB[e] = 0.0f; }

    float hA[2][8], hB[2][8];   // 2-slot rotation per row (static idx)

    auto loadH = [&](const float* hrow, int x, float* h) {
        int s = 32 * x + col;
        if (32 * x + 31 >= SS) s = min(s, SS - 1);      // folds away except x=6
        const float4* p = reinterpret_cast<const float4*>(hrow + (size_t)s * 8);
        float4 v0 = p[0], v1 = p[1];
        h[0]=v0.x; h[1]=v0.y; h[2]=v0.z; h[3]=v0.w;
        h[4]=v1.x; h[5]=v1.y; h[6]=v1.z; h[7]=v1.w;
    };

    // full per-row chain (S1 -> S2 -> score -> pool); rows are independent
    auto CH = [&](const float* h, const short8* a1f, const unsigned* uqc,
                  float* acc, int len, int x) {
        union u_s8 { unsigned u[4]; short8 s; };
        u_s8 ubf;
        ubf.u[0] = hi ? uqc[0] : packbf2(h[0], h[1]);
        ubf.u[1] = hi ? uqc[1] : packbf2(h[2], h[3]);
        ubf.u[2] = hi ? uqc[2] : packbf2(h[4], h[5]);
        ubf.u[3] = hi ? uqc[3] : packbf2(h[6], h[7]);

        f32x16 a1_0 = __builtin_amdgcn_mfma_f32_32x32x16_bf16(a1f[0], ubf.s, b1c16[0], 0, 0, 0);
        f32x16 a1_1 = __builtin_amdgcn_mfma_f32_32x32x16_bf16(a1f[1], ubf.s, b1c16[1], 0, 0, 0);

        u_s8 bB[4];
#pragma unroll
        for (int m = 0; m < 4; ++m) {
#pragma unroll
            for (int d = 0; d < 4; ++d) {
                int p0 = 8 * (m & 1) + 2 * d;
                float lo, hi2;
                if (m >> 1) { lo = a1_1[p0]; hi2 = a1_1[p0 + 1]; }
                else        { lo = a1_0[p0]; hi2 = a1_0[p0 + 1]; }
                bB[m].u[d] = packbf2(fmaxf(lo, 0.f), fmaxf(hi2, 0.f));
            }
        }

        f32x16 a2 = __builtin_amdgcn_mfma_f32_32x32x16_bf16(w2f[0], bB[0].s, b2c16, 0, 0, 0);
        a2 = __builtin_amdgcn_mfma_f32_32x32x16_bf16(w2f[1], bB[1].s, a2, 0, 0, 0);
        a2 = __builtin_amdgcn_mfma_f32_32x32x16_bf16(w2f[2], bB[2].s, a2, 0, 0, 0);
        a2 = __builtin_amdgcn_mfma_f32_32x32x16_bf16(w2f[3], bB[3].s, a2, 0, 0, 0);

        float s0 = 0.f, s1 = 0.f, s2 = 0.f, s3 = 0.f;
#pragma unroll
        for (int r = 0; r < 4; ++r) {
            s0 = fmaf(fmaxf(a2[r],      0.f), W3v16[r],      s0);
            s1 = fmaf(fmaxf(a2[4 + r],  0.f), W3v16[4 + r],  s1);
            s2 = fmaf(fmaxf(a2[8 + r],  0.f), W3v16[8 + r],  s2);
            s3 = fmaf(fmaxf(a2[12 + r], 0.f), W3v16[12 + r], s3);
        }
        float p = (s0 + s1) + (s2 + s3);
        p += __shfl_xor(p, 32);
        float sc = (32 * x + col < len) ? (p + b3s) : 0.0f;
#pragma unroll
        for (int e = 0; e < 8; ++e) acc[e] = fmaf(sc, h[e], acc[e]);
    };

    // pipeline: load(t+1) both rows | chain r0(t) | chain r1(t) — fully unrolled
    loadH(hrow0, 0, hA[0]);
    loadH(hrow1, 0, hB[0]);
#pragma unroll
    for (int it = 0; it < 7; ++it) {
        if (it + 1 < 7) {
            loadH(hrow0, it + 1, hA[(it + 1) & 1]);
            loadH(hrow1, it + 1, hB[(it + 1) & 1]);
        }
        CH(hA[it & 1], a1fA, uqcA, accA, len0, it);
        CH(hB[it & 1], a1fB, uqcB, accB, len1, it);
    }

    // reduce over the 32 position-lanes (hi-copies identical)
#pragma unroll
    for (int m = 1; m < 32; m <<= 1)
#pragma unroll
        for (int e = 0; e < 8; ++e) {
            accA[e] += __shfl_xor(accA[e], m);
            accB[e] += __shfl_xor(accB[e], m);
        }

    if (l == 0) {
        float4* op0 = reinterpret_cast<float4*>(out + (size_t)brow0 * 8);
        op0[0] = make_float4(accA[0], accA[1], accA[2], accA[3]);
        op0[1] = make_float4(accA[4], accA[5], accA[6], accA[7]);
        float4* op1 = reinterpret_cast<float4*>(out + (size_t)brow1 * 8);
        op1[0] = make_float4(accB[0], accB[1], accB[2], accB[3]);
        op1[1] = make_float4(accB[4], accB[5], accB[6], accB[7]);
    }
}

extern "C" void kernel_launch(void* const* d_in, const int* in_sizes, int n_in,
                              void* d_out, int out_size, void* d_ws, size_t ws_size,
                              hipStream_t stream) {
    const float* query = (const float*)d_in[0];
    const float* hist  = (const float*)d_in[1];
    const int*   hlen  = (const int*)d_in[2];
    const float* W1    = (const float*)d_in[3];
    const float* b1    = (const float*)d_in[4];
    const float* W2    = (const float*)d_in[5];
    const float* b2    = (const float*)d_in[6];
    const float* W3    = (const float*)d_in[7];
    const float* b3    = (const float*)d_in[8];
    float*       out   = (float*)d_out;

    char* w = (char*)d_ws;
    float*          wsA   = (float*)(w);                    // 8192 B
    float*          wsb1p = (float*)(w + 8192);             // 256 B
    unsigned short* wsW2f = (unsigned short*)(w + 8448);    // 4096 B

    prep_kernel<<<1, 256, 0, stream>>>(W1, W2, b1, wsA, wsb1p, wsW2f);
    din13_kernel<<<BB / 8, 256, 0, stream>>>(query, hist, hlen, wsA, wsb1p, wsW2f,
                                             b2, W3, b3, out);
}